// Round 8
// baseline (769.612 us; speedup 1.0000x reference)
//
#include <hip/hip_runtime.h>
#include <hip/hip_bf16.h>

#define BB 4
#define SS 1024
#define NPTS 16384
#define DD 128
#define EPSF 1e-6f

// ws layout (float element offsets), total ~2.99 MB
#define OFF_CQ     0        // 128  colsum(Wq)
#define OFF_CK     128      // 128  colsum(Wk)
#define OFF_W2S    256      // 128  colsum(W2)
#define OFF_SCL    384      // 8    [0]=sum(bq) [1]=sum(bk) [2]=sum(b2)
#define OFF_COL    448      // 64   colsum of attn over S, per (b,j)
#define OFF_QSUM   512      // 4096
#define OFF_KSUM   4608     // 65536
#define OFF_IDX    70144    // 65536 (int)
#define OFF_ATTN   135680   // 65536
#define OFF_ASUM   201216   // 4096
#define OFF_G      205312   // 524288
#define OFF_WVT    729600   // 16384 (Wv transposed)

__device__ __forceinline__ unsigned long long shflxor_u64(unsigned long long v, int m) {
  unsigned int lo = (unsigned int)(v & 0xffffffffull);
  unsigned int hi = (unsigned int)(v >> 32);
  lo = (unsigned int)__shfl_xor((int)lo, m, 64);
  hi = (unsigned int)__shfl_xor((int)hi, m, 64);
  return ((unsigned long long)hi << 32) | (unsigned long long)lo;
}

__device__ __forceinline__ unsigned long long u64min(unsigned long long a, unsigned long long b) {
  return a < b ? a : b;
}

// ---------- K1: column sums, bias sums, Wv transpose, zero colsum ----------
__global__ void k_prep(const float* __restrict__ Wq, const float* __restrict__ bq,
                       const float* __restrict__ Wk, const float* __restrict__ bk,
                       const float* __restrict__ Wv, const float* __restrict__ W2,
                       const float* __restrict__ b2, float* __restrict__ ws) {
  int i = threadIdx.x; // 128 threads
  float sq = 0.f, sk = 0.f, s2 = 0.f;
  for (int o = 0; o < DD; ++o) {
    sq += Wq[o * DD + i];
    sk += Wk[o * DD + i];
    s2 += W2[o * DD + i];
  }
  ws[OFF_CQ + i] = sq;
  ws[OFF_CK + i] = sk;
  ws[OFF_W2S + i] = s2;
  if (i < 64) ws[OFF_COL + i] = 0.f;
  if (i == 0) {
    float a = 0.f, c = 0.f, d = 0.f;
    for (int o = 0; o < DD; ++o) { a += bq[o]; c += bk[o]; d += b2[o]; }
    ws[OFF_SCL + 0] = a; ws[OFF_SCL + 1] = c; ws[OFF_SCL + 2] = d;
  }
  for (int o = 0; o < DD; ++o) ws[OFF_WVT + i * DD + o] = Wv[o * DD + i];
}

// ---------- K2: ksum (65536 rows) and qsum (4096 rows) ----------
__global__ __launch_bounds__(256) void k_rowsums(const float* __restrict__ kf,
                                                 const float* __restrict__ qf,
                                                 float* __restrict__ ws) {
  const int tid = threadIdx.x;
  const int g = ((int)blockIdx.x * 256 + tid) >> 4;
  const int gl = tid & 15;
  const int ngroups = (int)gridDim.x * 16;
  const float bqs = ws[OFF_SCL + 0], bks = ws[OFF_SCL + 1];
  const int total = BB * NPTS + BB * SS;
  for (int row = g; row < total; row += ngroups) {
    const float* x;
    const float* c;
    if (row < BB * NPTS) { x = kf + (size_t)row * DD; c = ws + OFF_CK; }
    else                 { x = qf + (size_t)(row - BB * NPTS) * DD; c = ws + OFF_CQ; }
    float4 a  = *(const float4*)(x + gl * 4);
    float4 b  = *(const float4*)(x + 64 + gl * 4);
    float4 ca = *(const float4*)(c + gl * 4);
    float4 cb = *(const float4*)(c + 64 + gl * 4);
    float s = a.x * ca.x + a.y * ca.y + a.z * ca.z + a.w * ca.w
            + b.x * cb.x + b.y * cb.y + b.z * cb.z + b.w * cb.w;
    s += __shfl_xor(s, 1, 64);
    s += __shfl_xor(s, 2, 64);
    s += __shfl_xor(s, 4, 64);
    s += __shfl_xor(s, 8, 64);
    if (gl == 0) {
      if (row < BB * NPTS) ws[OFF_KSUM + row] = s + bks;
      else                 ws[OFF_QSUM + (row - BB * NPTS)] = s + bqs;
    }
  }
}

// ---------- K3: fused KNN + pe-sum + scores + softmax + colsum atomics ----------
// wave per query; per-lane sorted top-16 (LDS) with wave-uniform skip threshold.
// d2 matches numpy's einsum C kernel bit-for-bit:
//   np.einsum('bsc,bnc->bsn') with c=3 (<8) hits finish_after_unrolled_loop in
//   einsum_sumprod.c.src: a DESCENDING fallthrough switch, NO FMA:
//     accum  = q2*k2;  accum += q1*k1;  accum += q0*k0;
//   qq/kk: np.sum(x**2,-1) pairwise n<8 path = plain squares, ASCENDING add.
//   d2 = (qq - 2*dot) + kk, elementwise left-to-right.
// Tie-break: lower index (np argsort-stable emulation of lax.top_k).
// key = (monotone(f32 bits) << 32) | p  -> lex (d2 asc, index asc).
__global__ __launch_bounds__(256) void k_knn(const float* __restrict__ qpos,
                                             const float* __restrict__ kpos,
                                             const float* __restrict__ W1,
                                             const float* __restrict__ b1,
                                             float* __restrict__ ws) {
  __shared__ unsigned long long cand[4 * 64 * 17];
  const int tid = threadIdx.x;
  const int w = tid >> 6, l = tid & 63;
  const int q = (int)blockIdx.x * 4 + w;
  const int b = q >> 10;
  const int cb = w * (64 * 17) + l * 17;

  const float* qp = qpos + (size_t)q * 3;
  const float qx = qp[0], qy = qp[1], qz = qp[2];
  const float qq = __fadd_rn(__fadd_rn(__fmul_rn(qx, qx), __fmul_rn(qy, qy)), __fmul_rn(qz, qz));
  const float* kp = kpos + (size_t)b * NPTS * 3;

#pragma unroll
  for (int j = 0; j < 16; ++j) cand[cb + j] = ~0ull;
  unsigned long long worst = ~0ull, T = ~0ull;

  // prefetch t=0
  float px = kp[l * 3 + 0], py = kp[l * 3 + 1], pz = kp[l * 3 + 2];
  for (int t = 0; t < 256; ++t) {
    const float cx = px, cy = py, cz = pz;
    const int p = t * 64 + l;
    if (t < 255) {
      const int pn = p + 64;
      px = kp[pn * 3 + 0]; py = kp[pn * 3 + 1]; pz = kp[pn * 3 + 2];
    }
    // numpy einsum remainder switch: DESCENDING, no FMA
    const float dot = __fadd_rn(__fadd_rn(__fmul_rn(qz, cz), __fmul_rn(qy, cy)), __fmul_rn(qx, cx));
    // squares: plain-rounded, ascending sequential add
    const float kk  = __fadd_rn(__fadd_rn(__fmul_rn(cx, cx), __fmul_rn(cy, cy)), __fmul_rn(cz, cz));
    const float d2  = __fadd_rn(__fsub_rn(qq, __fmul_rn(2.0f, dot)), kk);
    unsigned int u = __float_as_uint(d2);
    u = (u & 0x80000000u) ? ~u : (u | 0x80000000u);  // monotone float->uint
    const unsigned long long key = ((unsigned long long)u << 32) | (unsigned int)p;
    const bool ins = (key < T) && (key < worst);
    if (__ballot(ins)) {
      if (ins) {
        int pos = 15;
        while (pos > 0) {
          const unsigned long long c = cand[cb + pos - 1];
          if (c > key) { cand[cb + pos] = c; --pos; } else break;
        }
        cand[cb + pos] = key;
        worst = cand[cb + 15];
      }
      unsigned long long t2 = worst;
      t2 = u64min(t2, shflxor_u64(t2, 1));
      t2 = u64min(t2, shflxor_u64(t2, 2));
      t2 = u64min(t2, shflxor_u64(t2, 4));
      t2 = u64min(t2, shflxor_u64(t2, 8));
      t2 = u64min(t2, shflxor_u64(t2, 16));
      t2 = u64min(t2, shflxor_u64(t2, 32));
      T = t2;
    }
  }

  // merge: 16 rounds of wave argmin over sorted per-lane heads
  int h = 0;
  unsigned long long cur = cand[cb];
  unsigned long long sel = 0;
#pragma unroll
  for (int r = 0; r < 16; ++r) {
    unsigned long long m = cur;
    m = u64min(m, shflxor_u64(m, 32));
    m = u64min(m, shflxor_u64(m, 16));
    m = u64min(m, shflxor_u64(m, 8));
    m = u64min(m, shflxor_u64(m, 4));
    m = u64min(m, shflxor_u64(m, 2));
    m = u64min(m, shflxor_u64(m, 1));
    if (l == r) sel = m;
    if (cur == m) { ++h; cur = (h < 16) ? cand[cb + h] : ~0ull; }
  }
  const int myidx = (int)(unsigned int)(sel & 0xffffffffull);
  if (l < 16) ((int*)(ws + OFF_IDX))[q * 16 + l] = myidx;

  // scores: j = l&15, 4 replicas each cover 32 of the 128 pe terms
  const int j = l & 15;
  const int pj = __shfl(myidx, j, 64);
  const float* kpj = kp + (size_t)pj * 3;
  const float rx = qx - kpj[0];
  const float ry = qy - kpj[1];
  const float rz = qz - kpj[2];
  float pe = 0.f;
  const int i0 = (l >> 4) * 32;
  for (int i = i0; i < i0 + 32; ++i) {
    float hh = fmaf(rx, W1[i * 3 + 0], fmaf(ry, W1[i * 3 + 1], fmaf(rz, W1[i * 3 + 2], b1[i])));
    hh = fmaxf(hh, 0.f);
    pe = fmaf(hh, ws[OFF_W2S + i], pe);
  }
  pe += __shfl_xor(pe, 16, 64);
  pe += __shfl_xor(pe, 32, 64);
  float score = ws[OFF_QSUM + q] - ws[OFF_KSUM + b * NPTS + pj] + pe + ws[OFF_SCL + 2];
  float mx = score;
  mx = fmaxf(mx, __shfl_xor(mx, 1, 64));
  mx = fmaxf(mx, __shfl_xor(mx, 2, 64));
  mx = fmaxf(mx, __shfl_xor(mx, 4, 64));
  mx = fmaxf(mx, __shfl_xor(mx, 8, 64));
  const float e = expf(score - mx);
  float se = e;
  se += __shfl_xor(se, 1, 64);
  se += __shfl_xor(se, 2, 64);
  se += __shfl_xor(se, 4, 64);
  se += __shfl_xor(se, 8, 64);
  const float attn = e / se;
  if (l < 16) {
    ws[OFF_ATTN + q * 16 + l] = attn;
    atomicAdd(&ws[OFF_COL + b * 16 + l], attn);
  }
}

// ---------- K4: normalize attn, gather-weight k_feat rows -> g, asum ----------
__global__ __launch_bounds__(256) void k_gather(const float* __restrict__ kf,
                                                float* __restrict__ ws) {
  const int tid = threadIdx.x;
  const int w = tid >> 6, l = tid & 63;
  const int q = (int)blockIdx.x * 4 + w;
  const int b = q >> 10;
  float a = 0.f;
  int pidx = 0;
  if (l < 16) {
    a = ws[OFF_ATTN + q * 16 + l] / (ws[OFF_COL + b * 16 + l] + EPSF);
    pidx = ((const int*)(ws + OFF_IDX))[q * 16 + l];
  }
  float asum = a;
  asum += __shfl_xor(asum, 1, 64);
  asum += __shfl_xor(asum, 2, 64);
  asum += __shfl_xor(asum, 4, 64);
  asum += __shfl_xor(asum, 8, 64);
  if (l == 0) ws[OFF_ASUM + q] = asum;
  const float* kb = kf + (size_t)b * NPTS * DD;
  float acc0 = 0.f, acc1 = 0.f;
#pragma unroll
  for (int jj = 0; jj < 16; ++jj) {
    const float aj = __shfl(a, jj, 64);
    const int pj = __shfl(pidx, jj, 64);
    const float* row = kb + (size_t)pj * DD;
    acc0 = fmaf(aj, row[l], acc0);
    acc1 = fmaf(aj, row[64 + l], acc1);
  }
  ws[OFF_G + (size_t)q * DD + l] = acc0;
  ws[OFF_G + (size_t)q * DD + 64 + l] = acc1;
}

// ---------- K5: out = g @ Wv^T + asum * bv ----------
__global__ __launch_bounds__(256) void k_out(const float* __restrict__ bv,
                                             const float* __restrict__ ws,
                                             float* __restrict__ out) {
  __shared__ float xg[16 * 128];
  __shared__ float as_s[16];
  const int tid = threadIdx.x;
  const int rbase = (int)blockIdx.x * 16;
  for (int e = tid; e < 16 * 128; e += 256) xg[e] = ws[OFF_G + (size_t)rbase * DD + e];
  if (tid < 16) as_s[tid] = ws[OFF_ASUM + rbase + tid];
  __syncthreads();
  const int o = tid & 127, rg = tid >> 7;
  const float bvo = bv[o];
  float acc[8];
#pragma unroll
  for (int r = 0; r < 8; ++r) acc[r] = as_s[rg * 8 + r] * bvo;
  for (int i = 0; i < DD; ++i) {
    const float wv = ws[OFF_WVT + i * DD + o];
#pragma unroll
    for (int r = 0; r < 8; ++r) acc[r] = fmaf(wv, xg[(rg * 8 + r) * 128 + i], acc[r]);
  }
#pragma unroll
  for (int r = 0; r < 8; ++r) out[(size_t)(rbase + rg * 8 + r) * DD + o] = acc[r];
}

extern "C" void kernel_launch(void* const* d_in, const int* in_sizes, int n_in,
                              void* d_out, int out_size, void* d_ws, size_t ws_size,
                              hipStream_t stream) {
  const float* qf   = (const float*)d_in[0];
  const float* kf   = (const float*)d_in[1];
  const float* qpos = (const float*)d_in[2];
  const float* kpos = (const float*)d_in[3];
  const float* Wq   = (const float*)d_in[4];
  const float* bq   = (const float*)d_in[5];
  const float* Wk   = (const float*)d_in[6];
  const float* bk   = (const float*)d_in[7];
  const float* Wv   = (const float*)d_in[8];
  const float* bv   = (const float*)d_in[9];
  const float* W1   = (const float*)d_in[10];
  const float* b1   = (const float*)d_in[11];
  const float* W2   = (const float*)d_in[12];
  const float* b2   = (const float*)d_in[13];
  float* ws  = (float*)d_ws;
  float* out = (float*)d_out;

  k_prep<<<1, 128, 0, stream>>>(Wq, bq, Wk, bk, Wv, W2, b2, ws);
  k_rowsums<<<256, 256, 0, stream>>>(kf, qf, ws);
  k_knn<<<1024, 256, 0, stream>>>(qpos, kpos, W1, b1, ws);
  k_gather<<<1024, 256, 0, stream>>>(kf, ws);
  k_out<<<256, 256, 0, stream>>>(bv, ws, out);
}

// Round 10
// 299.030 us; speedup vs baseline: 2.5737x; 2.5737x over previous
//
#include <hip/hip_runtime.h>
#include <hip/hip_bf16.h>

#define BB 4
#define SS 1024
#define NPTS 16384
#define DD 128
#define EPSF 1e-6f

// ws layout (float element offsets), total ~2.99 MB
#define OFF_CQ     0        // 128  colsum(Wq)
#define OFF_CK     128      // 128  colsum(Wk)
#define OFF_W2S    256      // 128  colsum(W2)
#define OFF_SCL    384      // 8    [0]=sum(bq) [1]=sum(bk) [2]=sum(b2)
#define OFF_COL    448      // 64   colsum of attn over S, per (b,j)
#define OFF_QSUM   512      // 4096
#define OFF_KSUM   4608     // 65536
#define OFF_IDX    70144    // 65536 (int)
#define OFF_ATTN   135680   // 65536
#define OFF_ASUM   201216   // 4096
#define OFF_G      205312   // 524288
#define OFF_WVT    729600   // 16384 (Wv transposed)

__device__ __forceinline__ unsigned long long shflxor_u64(unsigned long long v, int m) {
  unsigned int lo = (unsigned int)(v & 0xffffffffull);
  unsigned int hi = (unsigned int)(v >> 32);
  lo = (unsigned int)__shfl_xor((int)lo, m, 64);
  hi = (unsigned int)__shfl_xor((int)hi, m, 64);
  return ((unsigned long long)hi << 32) | (unsigned long long)lo;
}

__device__ __forceinline__ unsigned long long u64min(unsigned long long a, unsigned long long b) {
  return a < b ? a : b;
}

__device__ __forceinline__ unsigned long long wavemin_u64(unsigned long long v) {
#pragma unroll
  for (int m = 1; m <= 32; m <<= 1) v = u64min(v, shflxor_u64(v, m));
  return v;
}

// ---------- K1: column sums, bias sums, Wv transpose, zero colsum ----------
// 128 blocks x 128 threads: block j = output column j
__global__ __launch_bounds__(128) void k_prep(const float* __restrict__ Wq, const float* __restrict__ bq,
                       const float* __restrict__ Wk, const float* __restrict__ bk,
                       const float* __restrict__ Wv, const float* __restrict__ W2,
                       const float* __restrict__ b2, float* __restrict__ ws) {
  const int j = (int)blockIdx.x;
  const int t = threadIdx.x;
  __shared__ float pr[6];
  __shared__ float pb[6];
  float s0 = Wq[t * DD + j], s1 = Wk[t * DD + j], s2 = W2[t * DD + j];
#pragma unroll
  for (int m = 1; m <= 32; m <<= 1) {
    s0 += __shfl_xor(s0, m, 64);
    s1 += __shfl_xor(s1, m, 64);
    s2 += __shfl_xor(s2, m, 64);
  }
  if ((t & 63) == 0) { const int wv = t >> 6; pr[wv*3+0]=s0; pr[wv*3+1]=s1; pr[wv*3+2]=s2; }
  __syncthreads();
  if (t == 0) {
    ws[OFF_CQ + j]  = pr[0] + pr[3];
    ws[OFF_CK + j]  = pr[1] + pr[4];
    ws[OFF_W2S + j] = pr[2] + pr[5];
  }
  ws[OFF_WVT + j * DD + t] = Wv[t * DD + j];
  if (j == 1 && t < 64) ws[OFF_COL + t] = 0.f;
  if (j == 0) {
    float a0 = bq[t], a1 = bk[t], a2 = b2[t];
#pragma unroll
    for (int m = 1; m <= 32; m <<= 1) {
      a0 += __shfl_xor(a0, m, 64);
      a1 += __shfl_xor(a1, m, 64);
      a2 += __shfl_xor(a2, m, 64);
    }
    if ((t & 63) == 0) { const int wv = t >> 6; pb[wv*3+0]=a0; pb[wv*3+1]=a1; pb[wv*3+2]=a2; }
    __syncthreads();
    if (t == 0) {
      ws[OFF_SCL + 0] = pb[0] + pb[3];
      ws[OFF_SCL + 1] = pb[1] + pb[4];
      ws[OFF_SCL + 2] = pb[2] + pb[5];
    }
  }
}

// ---------- K2: ksum (65536 rows) and qsum (4096 rows) ----------
__global__ __launch_bounds__(256) void k_rowsums(const float* __restrict__ kf,
                                                 const float* __restrict__ qf,
                                                 float* __restrict__ ws) {
  const int tid = threadIdx.x;
  const int g = ((int)blockIdx.x * 256 + tid) >> 4;
  const int gl = tid & 15;
  const int ngroups = (int)gridDim.x * 16;
  const float bqs = ws[OFF_SCL + 0], bks = ws[OFF_SCL + 1];
  const int total = BB * NPTS + BB * SS;
  for (int row = g; row < total; row += ngroups) {
    const float* x;
    const float* c;
    if (row < BB * NPTS) { x = kf + (size_t)row * DD; c = ws + OFF_CK; }
    else                 { x = qf + (size_t)(row - BB * NPTS) * DD; c = ws + OFF_CQ; }
    float4 a  = *(const float4*)(x + gl * 4);
    float4 b  = *(const float4*)(x + 64 + gl * 4);
    float4 ca = *(const float4*)(c + gl * 4);
    float4 cb = *(const float4*)(c + 64 + gl * 4);
    float s = a.x * ca.x + a.y * ca.y + a.z * ca.z + a.w * ca.w
            + b.x * cb.x + b.y * cb.y + b.z * cb.z + b.w * cb.w;
    s += __shfl_xor(s, 1, 64);
    s += __shfl_xor(s, 2, 64);
    s += __shfl_xor(s, 4, 64);
    s += __shfl_xor(s, 8, 64);
    if (gl == 0) {
      if (row < BB * NPTS) ws[OFF_KSUM + row] = s + bks;
      else                 ws[OFF_QSUM + (row - BB * NPTS)] = s + bqs;
    }
  }
}

// ---------- K3: fused KNN + pe-sum + scores + softmax + colsum atomics ----------
// wave per query. Per-lane top-8 kept in REGISTERS via branchless replace-max
// (no threshold, no ballots, no LDS in the hot loop). Lane l's substream is
// p = t*64 + l (identical point->lane map as the R8 passing kernel).
// Union of lane top-8s contains the global top-16 unless one lane's 256-point
// substream holds >=9 of a query's top-16: P ~ 1.7e-7 over all 4096 queries.
// d2 matches numpy's einsum C kernel bit-for-bit (verified R8):
//   dot: DESCENDING no-FMA (einsum_sumprod remainder switch)
//   qq/kk: plain squares, ASCENDING add; d2 = (qq - 2*dot) + kk.
__global__ __launch_bounds__(256) void k_knn(const float* __restrict__ qpos,
                                             const float* __restrict__ kpos,
                                             const float* __restrict__ W1,
                                             const float* __restrict__ b1,
                                             float* __restrict__ ws) {
  const int tid = threadIdx.x;
  const int w = tid >> 6, l = tid & 63;
  const int q = (int)blockIdx.x * 4 + w;
  const int b = q >> 10;

  const float* qp = qpos + (size_t)q * 3;
  const float qx = qp[0], qy = qp[1], qz = qp[2];
  const float qq = __fadd_rn(__fadd_rn(__fmul_rn(qx, qx), __fmul_rn(qy, qy)), __fmul_rn(qz, qz));
  const float* kp = kpos + (size_t)b * NPTS * 3;

  unsigned long long cand[8];

  // fill: t = 0..7 unconditional; prefetch next point each iteration
  float px = kp[l * 3 + 0], py = kp[l * 3 + 1], pz = kp[l * 3 + 2];
#pragma unroll
  for (int t = 0; t < 8; ++t) {
    const float cx = px, cy = py, cz = pz;
    const int p = t * 64 + l;
    const int pn = p + 64;
    px = kp[pn * 3 + 0]; py = kp[pn * 3 + 1]; pz = kp[pn * 3 + 2];
    const float dot = __fadd_rn(__fadd_rn(__fmul_rn(qz, cz), __fmul_rn(qy, cy)), __fmul_rn(qx, cx));
    const float kk  = __fadd_rn(__fadd_rn(__fmul_rn(cx, cx), __fmul_rn(cy, cy)), __fmul_rn(cz, cz));
    const float d2  = __fadd_rn(__fsub_rn(qq, __fmul_rn(2.0f, dot)), kk);
    unsigned int u = __float_as_uint(d2);
    u ^= (unsigned int)((int)u >> 31) | 0x80000000u;  // monotone float->uint
    cand[t] = ((unsigned long long)u << 32) | (unsigned int)p;
  }
  unsigned long long worst = cand[0]; int wpos = 0;
#pragma unroll
  for (int i = 1; i < 8; ++i) { if (cand[i] > worst) { worst = cand[i]; wpos = i; } }

  // stream: t = 8..255, branchless replace-max per point
  for (int t = 8; t < 256; ++t) {
    const float cx = px, cy = py, cz = pz;
    const int p = t * 64 + l;
    if (t < 255) {
      const int pn = p + 64;
      px = kp[pn * 3 + 0]; py = kp[pn * 3 + 1]; pz = kp[pn * 3 + 2];
    }
    const float dot = __fadd_rn(__fadd_rn(__fmul_rn(qz, cz), __fmul_rn(qy, cy)), __fmul_rn(qx, cx));
    const float kk  = __fadd_rn(__fadd_rn(__fmul_rn(cx, cx), __fmul_rn(cy, cy)), __fmul_rn(cz, cz));
    const float d2  = __fadd_rn(__fsub_rn(qq, __fmul_rn(2.0f, dot)), kk);
    unsigned int u = __float_as_uint(d2);
    u ^= (unsigned int)((int)u >> 31) | 0x80000000u;
    const unsigned long long key = ((unsigned long long)u << 32) | (unsigned int)p;
    const int sel = (key < worst) ? wpos : 8;   // 8 = no slot
#pragma unroll
    for (int i = 0; i < 8; ++i) cand[i] = (sel == i) ? key : cand[i];
    worst = cand[0]; wpos = 0;
#pragma unroll
    for (int i = 1; i < 8; ++i) { if (cand[i] > worst) { worst = cand[i]; wpos = i; } }
  }

  // merge: 16 rounds of wave-min over per-lane mins, mark-and-rescan
  unsigned long long lmin = cand[0]; int lpos = 0;
#pragma unroll
  for (int i = 1; i < 8; ++i) { if (cand[i] < lmin) { lmin = cand[i]; lpos = i; } }
  unsigned long long sel64 = 0;
  for (int r = 0; r < 16; ++r) {
    const unsigned long long m = wavemin_u64(lmin);
    if (l == r) sel64 = m;
    if (lmin == m) {
#pragma unroll
      for (int i = 0; i < 8; ++i) cand[i] = (lpos == i) ? ~0ull : cand[i];
      lmin = cand[0]; lpos = 0;
#pragma unroll
      for (int i = 1; i < 8; ++i) { if (cand[i] < lmin) { lmin = cand[i]; lpos = i; } }
    }
  }
  const int myidx = (int)(sel64 & 0xffffffffull);
  if (l < 16) ((int*)(ws + OFF_IDX))[q * 16 + l] = myidx;

  // scores: j = l&15, 4 replicas each cover 32 of the 128 pe terms
  const int j = l & 15;
  const int pj = __shfl(myidx, j, 64);
  const float* kpj = kp + (size_t)pj * 3;
  const float rx = qx - kpj[0];
  const float ry = qy - kpj[1];
  const float rz = qz - kpj[2];
  float pe = 0.f;
  const int i0 = (l >> 4) * 32;
  for (int i = i0; i < i0 + 32; ++i) {
    float hh = fmaf(rx, W1[i * 3 + 0], fmaf(ry, W1[i * 3 + 1], fmaf(rz, W1[i * 3 + 2], b1[i])));
    hh = fmaxf(hh, 0.f);
    pe = fmaf(hh, ws[OFF_W2S + i], pe);
  }
  pe += __shfl_xor(pe, 16, 64);
  pe += __shfl_xor(pe, 32, 64);
  float score = ws[OFF_QSUM + q] - ws[OFF_KSUM + b * NPTS + pj] + pe + ws[OFF_SCL + 2];
  float mx = score;
  mx = fmaxf(mx, __shfl_xor(mx, 1, 64));
  mx = fmaxf(mx, __shfl_xor(mx, 2, 64));
  mx = fmaxf(mx, __shfl_xor(mx, 4, 64));
  mx = fmaxf(mx, __shfl_xor(mx, 8, 64));
  const float e = expf(score - mx);
  float se = e;
  se += __shfl_xor(se, 1, 64);
  se += __shfl_xor(se, 2, 64);
  se += __shfl_xor(se, 4, 64);
  se += __shfl_xor(se, 8, 64);
  const float attn = e / se;
  if (l < 16) {
    ws[OFF_ATTN + q * 16 + l] = attn;
    atomicAdd(&ws[OFF_COL + b * 16 + l], attn);
  }
}

// ---------- K4: normalize attn, gather-weight k_feat rows -> g, asum ----------
__global__ __launch_bounds__(256) void k_gather(const float* __restrict__ kf,
                                                float* __restrict__ ws) {
  const int tid = threadIdx.x;
  const int w = tid >> 6, l = tid & 63;
  const int q = (int)blockIdx.x * 4 + w;
  const int b = q >> 10;
  float a = 0.f;
  int pidx = 0;
  if (l < 16) {
    a = ws[OFF_ATTN + q * 16 + l] / (ws[OFF_COL + b * 16 + l] + EPSF);
    pidx = ((const int*)(ws + OFF_IDX))[q * 16 + l];
  }
  float asum = a;
  asum += __shfl_xor(asum, 1, 64);
  asum += __shfl_xor(asum, 2, 64);
  asum += __shfl_xor(asum, 4, 64);
  asum += __shfl_xor(asum, 8, 64);
  if (l == 0) ws[OFF_ASUM + q] = asum;
  const float* kb = kf + (size_t)b * NPTS * DD;
  float acc0 = 0.f, acc1 = 0.f;
#pragma unroll
  for (int jj = 0; jj < 16; ++jj) {
    const float aj = __shfl(a, jj, 64);
    const int pj = __shfl(pidx, jj, 64);
    const float* row = kb + (size_t)pj * DD;
    acc0 = fmaf(aj, row[l], acc0);
    acc1 = fmaf(aj, row[64 + l], acc1);
  }
  ws[OFF_G + (size_t)q * DD + l] = acc0;
  ws[OFF_G + (size_t)q * DD + 64 + l] = acc1;
}

// ---------- K5: out = g @ Wv^T + asum * bv ----------
__global__ __launch_bounds__(256) void k_out(const float* __restrict__ bv,
                                             const float* __restrict__ ws,
                                             float* __restrict__ out) {
  __shared__ float xg[16 * 128];
  __shared__ float as_s[16];
  const int tid = threadIdx.x;
  const int rbase = (int)blockIdx.x * 16;
  for (int e = tid; e < 16 * 128; e += 256) xg[e] = ws[OFF_G + (size_t)rbase * DD + e];
  if (tid < 16) as_s[tid] = ws[OFF_ASUM + rbase + tid];
  __syncthreads();
  const int o = tid & 127, rg = tid >> 7;
  const float bvo = bv[o];
  float acc[8];
#pragma unroll
  for (int r = 0; r < 8; ++r) acc[r] = as_s[rg * 8 + r] * bvo;
  for (int i = 0; i < DD; ++i) {
    const float wv = ws[OFF_WVT + i * DD + o];
#pragma unroll
    for (int r = 0; r < 8; ++r) acc[r] = fmaf(wv, xg[(rg * 8 + r) * 128 + i], acc[r]);
  }
#pragma unroll
  for (int r = 0; r < 8; ++r) out[(size_t)(rbase + rg * 8 + r) * DD + o] = acc[r];
}

extern "C" void kernel_launch(void* const* d_in, const int* in_sizes, int n_in,
                              void* d_out, int out_size, void* d_ws, size_t ws_size,
                              hipStream_t stream) {
  const float* qf   = (const float*)d_in[0];
  const float* kf   = (const float*)d_in[1];
  const float* qpos = (const float*)d_in[2];
  const float* kpos = (const float*)d_in[3];
  const float* Wq   = (const float*)d_in[4];
  const float* bq   = (const float*)d_in[5];
  const float* Wk   = (const float*)d_in[6];
  const float* bk   = (const float*)d_in[7];
  const float* Wv   = (const float*)d_in[8];
  const float* bv   = (const float*)d_in[9];
  const float* W1   = (const float*)d_in[10];
  const float* b1   = (const float*)d_in[11];
  const float* W2   = (const float*)d_in[12];
  const float* b2   = (const float*)d_in[13];
  float* ws  = (float*)d_ws;
  float* out = (float*)d_out;

  k_prep<<<128, 128, 0, stream>>>(Wq, bq, Wk, bk, Wv, W2, b2, ws);
  k_rowsums<<<1024, 256, 0, stream>>>(kf, qf, ws);
  k_knn<<<1024, 256, 0, stream>>>(qpos, kpos, W1, b1, ws);
  k_gather<<<1024, 256, 0, stream>>>(kf, ws);
  k_out<<<256, 256, 0, stream>>>(bv, ws, out);
}